// Round 7
// baseline (194.307 us; speedup 1.0000x reference)
//
#include <hip/hip_runtime.h>

// ---- types -----------------------------------------------------------------
typedef __bf16 bf16;
typedef __attribute__((ext_vector_type(8))) __bf16 bf16x8;
typedef __attribute__((ext_vector_type(4))) __bf16 bf16x4;
typedef __attribute__((ext_vector_type(4))) float  f32x4;

static __device__ __forceinline__ f32x4 mfma16(bf16x8 a, bf16x8 b, f32x4 c) {
  return __builtin_amdgcn_mfma_f32_16x16x32_bf16(a, b, c, 0, 0, 0);
}
static __device__ __forceinline__ float fexp2(float x) {
  return __builtin_amdgcn_exp2f(x);
}

// exp(s/sqrt(128)) = exp2(s * C1)
#define EXP_C1 (1.4426950408889634f / 11.313708498984760f)

// async global->LDS, 16B/lane; dst base is wave-uniform, HW adds lane*16.
typedef const __attribute__((address_space(1))) unsigned int gas_u32;
typedef __attribute__((address_space(3))) unsigned int las_u32;
#define GLDS16(gp, lp) __builtin_amdgcn_global_load_lds((gas_u32*)(gp), (las_u32*)(lp), 16, 0, 0)

// RACE FIX (r4->r5, keep): drain own vmcnt BEFORE s_barrier so cross-wave
// DMA completion is guaranteed.
#define DMA_FENCE() __asm__ volatile("s_waitcnt vmcnt(0)" ::: "memory")

// Granule-major tile (128 rows x 128 cols bf16, 32KB): elem(r,c) = (c>>3)*1024 + r*8 + (c&7).
// V is ROW-PERMUTED (k_qkv epilogue) so PV consumes the QK^T C-fragment from
// registers: slot (quad,e) of 32-block s holds V row k = 32s + quad*4 + (e&3) + 16*(e>>2).
// XCD swizzle (keep): grids (64 b, T) with b on X -> same-b blocks share an XCD L2.
// R6->R7: occupancy 8 -> 16 waves/CU everywhere (512-thread blocks for
// stats/attn with 16-row waves; 64-row 33KB-LDS tiles for qkv -> 4 blocks/CU).

// ============================================================================
// Kernel 0: prep. W[3][128][256] fp32 -> Wc[3][32 g][128 n][8] bf16.
// ============================================================================
__global__ __launch_bounds__(256) void k_prep(
    const float* __restrict__ Wq, const float* __restrict__ Wk,
    const float* __restrict__ Wv, bf16* __restrict__ Wc)
{
  int id = blockIdx.x * 256 + threadIdx.x;      // 48 blocks = 3*4096
  int proj = id >> 12, r = id & 4095;
  int g = r >> 7, n = r & 127;
  const float* W = proj == 0 ? Wq : proj == 1 ? Wk : Wv;
  const float4* src = (const float4*)(W + n * 256 + g * 8);
  float4 a = src[0], b = src[1];
  bf16x8 o = { (bf16)a.x, (bf16)a.y, (bf16)a.z, (bf16)a.w,
               (bf16)b.x, (bf16)b.y, (bf16)b.z, (bf16)b.w };
  *(bf16x8*)(Wc + (size_t)proj * 32768 + g * 1024 + n * 8) = o;
}

// ============================================================================
// Kernel 1: QKV projection. grid(1024) 64-row tiles, block 256, LDS 33KB ->
// 4 blocks/CU (16 waves/CU). Stage 64x256 q fp32->bf16 once (padded granule
// chunks, stride 520 elems: fragment reads 2-way = free). Waves: (dh,sh) =
// 64-d x 32-s. Q/K swapped operands (C-regs = 4 consecutive d, packed stores).
// ============================================================================
__global__ __launch_bounds__(256, 4) void k_qkv(
    const float* __restrict__ q, const bf16* __restrict__ Wc,
    const float* __restrict__ bq, const float* __restrict__ bk, const float* __restrict__ bv,
    bf16* __restrict__ Qb, bf16* __restrict__ Kb, bf16* __restrict__ VT)
{
  __shared__ bf16 Al[32 * 520];                 // 32 granules x (64 rows x 8 + 8 pad)

  const int tid = threadIdx.x, lane = tid & 63, wave = tid >> 6;
  const int ln = lane & 15, quad = lane >> 4;
  const int sh = wave & 1, dh = wave >> 1;      // 32-s half, 64-d half
  const int m0 = blockIdx.x * 64;

  { // stage: 16 coalesced float4/thread -> bf16 chunks
    const float* src = q + (size_t)m0 * 256;
    for (int it = 0; it < 16; ++it) {
      int f = it * 1024 + tid * 4;
      int r = f >> 8, c = f & 255;
      float4 v = *(const float4*)(src + f);
      bf16x4 o = { (bf16)v.x, (bf16)v.y, (bf16)v.z, (bf16)v.w };
      *(bf16x4*)&Al[(c >> 3) * 520 + r * 8 + (c & 7)] = o;
    }
  }
  __syncthreads();

  const int b = m0 >> 10, st = (m0 & 1023) >> 7, s64 = m0 & 64;
  const size_t tbase = ((size_t)b * 8 + st) * 16384;

  for (int p = 0; p < 2; ++p) {                 // Q, K: D[d][s], A=W
    const bf16* W = Wc + (size_t)p * 32768;
    const float* bias = p == 0 ? bq : bk;
    f32x4 acc[4][2] = {};
    for (int kk = 0; kk < 8; ++kk) {
      int g = kk * 4 + quad;
      bf16x8 ax[2], bw[4];
      for (int j = 0; j < 2; ++j)
        ax[j] = *(const bf16x8*)&Al[g * 520 + (sh * 32 + j * 16 + ln) * 8];
      for (int i = 0; i < 4; ++i)
        bw[i] = *(const bf16x8*)(W + g * 1024 + (dh * 64 + i * 16 + ln) * 8);
      for (int i = 0; i < 4; ++i)
        for (int j = 0; j < 2; ++j)
          acc[i][j] = mfma16(bw[i], ax[j], acc[i][j]);
    }
    bf16* dst = (p == 0 ? Qb : Kb) + tbase;
    for (int i = 0; i < 4; ++i) {
      float4 b4 = *(const float4*)&bias[dh * 64 + i * 16 + quad * 4];
      int gd = dh * 8 + i * 2 + (quad >> 1);
      int e0 = (quad & 1) * 4;
      for (int j = 0; j < 2; ++j) {
        int s = s64 + sh * 32 + j * 16 + ln;
        bf16x4 o = { (bf16)(acc[i][j][0] + b4.x), (bf16)(acc[i][j][1] + b4.y),
                     (bf16)(acc[i][j][2] + b4.z), (bf16)(acc[i][j][3] + b4.w) };
        *(bf16x4*)&dst[(size_t)gd * 1024 + (size_t)s * 8 + e0] = o;
      }
    }
  }
  {                                             // V: D[s][d], row-permuted store
    const bf16* W = Wc + (size_t)2 * 32768;
    f32x4 acc[2][4] = {};
    for (int kk = 0; kk < 8; ++kk) {
      int g = kk * 4 + quad;
      bf16x8 ax[2], bw[4];
      for (int i = 0; i < 2; ++i)
        ax[i] = *(const bf16x8*)&Al[g * 520 + (sh * 32 + i * 16 + ln) * 8];
      for (int j = 0; j < 4; ++j)
        bw[j] = *(const bf16x8*)(W + g * 1024 + (dh * 64 + j * 16 + ln) * 8);
      for (int i = 0; i < 2; ++i)
        for (int j = 0; j < 4; ++j)
          acc[i][j] = mfma16(ax[i], bw[j], acc[i][j]);
    }
    bf16* dst = VT + tbase;
    for (int j = 0; j < 4; ++j) {
      int d = dh * 64 + j * 16 + ln;
      float bb = bv[d];
      for (int i = 0; i < 2; ++i) {
        int s0 = s64 + sh * 32 + i * 16 + quad * 4;
        int G  = (s0 >> 5) * 4 + ((s0 & 15) >> 2);
        int e0 = (s0 & 16) >> 2;
        bf16x4 o = { (bf16)(acc[i][j][0] + bb), (bf16)(acc[i][j][1] + bb),
                     (bf16)(acc[i][j][2] + bb), (bf16)(acc[i][j][3] + bb) };
        *(bf16x4*)&dst[(size_t)G * 1024 + (size_t)d * 8 + e0] = o;
      }
    }
  }
}

// ============================================================================
// Kernel 2: column stats. grid(64 b, 8 kt), block 512 (8 waves x 16 k-rows),
// 2 blocks/CU = 16 waves/CU. K-frags register-resident; Q streamed via
// double-buffered DMA shared by 8 waves. Colsum reduced by shfl only.
// ============================================================================
__global__ __launch_bounds__(512, 4) void k_stats(
    const bf16* __restrict__ Qb, const bf16* __restrict__ Kb, float* __restrict__ inv)
{
  __shared__ char Qbuf[2][32768];
  const int b = blockIdx.x, kt = blockIdx.y;
  const int tid = threadIdx.x, lane = tid & 63, wave = tid >> 6;   // wave 0..7
  const int ln = lane & 15, quad = lane >> 4;

  const bf16* ktile = Kb + ((size_t)b * 8 + kt) * 16384;
  bf16x8 ak[4];                                 // wave's 16 k-rows, full d=128
  for (int kk = 0; kk < 4; ++kk)
    ak[kk] = *(const bf16x8*)(ktile + (kk * 4 + quad) * 1024 + (wave * 16 + ln) * 8);

  const char* qb_b = (const char*)(Qb + (size_t)b * 8 * 16384);
  for (int c = 0; c < 4; ++c)                   // prologue DMA q-tile 0 (32 chunks/8 waves)
    GLDS16(qb_b + (wave * 4 + c) * 1024 + lane * 16, &Qbuf[0][(wave * 4 + c) * 1024]);

  f32x4 csum = {};
  for (int qt = 0; qt < 8; ++qt) {
    DMA_FENCE();
    __syncthreads();                            // all waves' DMA(qt) complete
    if (qt < 7)
      for (int c = 0; c < 4; ++c)
        GLDS16(qb_b + (size_t)(qt + 1) * 32768 + (wave * 4 + c) * 1024 + lane * 16,
               &Qbuf[(qt + 1) & 1][(wave * 4 + c) * 1024]);
    const char* Ql = Qbuf[qt & 1];
    for (int jq = 0; jq < 8; ++jq) {
      f32x4 s0 = {};
      for (int kk = 0; kk < 4; ++kk) {
        bf16x8 bqf = *(const bf16x8*)(Ql + ((kk * 4 + quad) * 2 + (jq >> 2)) * 1024
                                         + ((jq * 16 + ln) & 63) * 16);
        s0 = mfma16(ak[kk], bqf, s0);
      }
      for (int rr = 0; rr < 4; ++rr)
        csum[rr] += fexp2(s0[rr] * EXP_C1);
    }
  }
  for (int rr = 0; rr < 4; ++rr) {              // reduce over q-cols (ln lanes)
    float v = csum[rr];
    v += __shfl_xor(v, 1, 64); v += __shfl_xor(v, 2, 64);
    v += __shfl_xor(v, 4, 64); v += __shfl_xor(v, 8, 64);
    csum[rr] = v;
  }
  if (ln == 0) {
    float* dst = inv + (size_t)b * 1024 + kt * 128 + wave * 16 + quad * 4;
    for (int rr = 0; rr < 4; ++rr)
      dst[rr] = 1.0f / csum[rr];
  }
}

// ============================================================================
// Kernel 3: fused S^T=K Q^T -> P=exp*inv (in regs) -> O += P Vc -> q-max.
// grid(64 b, 8 qt), block 512 (8 waves x 16 q-rows, each wave full 64 k),
// 2 blocks/CU = 16 waves/CU. Double-buffered K/V DMA shared by 8 waves,
// one barrier + fence per k-tile. P repack via permuted-V contraction order.
// ============================================================================
__global__ __launch_bounds__(512, 4) void k_attn(
    const bf16* __restrict__ Qb, const bf16* __restrict__ Kb, const bf16* __restrict__ VT,
    const float* __restrict__ inv, float* __restrict__ Opart)
{
  __shared__ char buf[2][32768];                // [0,16K)=K chunks, [16K,32K)=V chunks
  __shared__ float invl[1024];
  __shared__ float redm[8][128];

  const int b = blockIdx.x, qt = blockIdx.y;
  const int tid = threadIdx.x, lane = tid & 63, wave = tid >> 6;   // wave 0..7
  const int ln = lane & 15, quad = lane >> 4;

  *(float2*)&invl[tid * 2] = *(const float2*)(inv + (size_t)b * 1024 + tid * 2);

  const bf16* qtile = Qb + ((size_t)b * 8 + qt) * 16384;
  bf16x8 bq_[4];                                // wave's 16 q-rows, full d
  for (int kk = 0; kk < 4; ++kk)
    bq_[kk] = *(const bf16x8*)(qtile + (kk * 4 + quad) * 1024 + (wave * 16 + ln) * 8);

  const char* kb_b = (const char*)(Kb + (size_t)b * 8 * 16384);
  const char* vt_b = (const char*)(VT + (size_t)b * 8 * 16384);

#define DMA_TILE(t) do {                                                         \
    const char* ksrc = kb_b + (size_t)((t) >> 1) * 32768 + ((t) & 1) * 1024;     \
    const char* vsrc = vt_b + (size_t)((t) >> 1) * 32768 + ((t) & 1) * 16384;    \
    char* d_ = buf[(t) & 1];                                                     \
    for (int c = 0; c < 2; ++c) {                                                \
      int ch = wave * 2 + c;                                                     \
      GLDS16(ksrc + ch * 2048 + lane * 16, d_ + ch * 1024);                      \
      GLDS16(vsrc + ch * 1024 + lane * 16, d_ + 16384 + ch * 1024);              \
    }                                                                            \
  } while (0)

  f32x4 oacc[8] = {};
  DMA_TILE(0);

  for (int t = 0; t < 16; ++t) {
    DMA_FENCE();
    __syncthreads();                            // all waves' DMA(t) complete
    if (t < 15) DMA_TILE(t + 1);
    const char* Kl = buf[t & 1];
    const char* Vl = buf[t & 1] + 16384;

    // S^T = K Q^T : 64 k x wave's 16 q. 16 MFMA.
    f32x4 sacc[4] = {};
    for (int kk = 0; kk < 4; ++kk) {
      for (int i = 0; i < 4; ++i) {
        bf16x8 akf = *(const bf16x8*)(Kl + (kk * 4 + quad) * 1024 + (i * 16 + ln) * 16);
        sacc[i] = mfma16(akf, bq_[kk], sacc[i]);
      }
    }
    // P = exp2(S*C1)*inv[k] -> PV A-frags in regs
    // (element e of step s: k = 32s + quad*4 + (e&3) + 16*(e>>2)).
    bf16x8 pf[2];
    for (int s = 0; s < 2; ++s) {
      float4 iv0 = *(float4*)&invl[t * 64 + (2 * s) * 16 + quad * 4];
      float4 iv1 = *(float4*)&invl[t * 64 + (2 * s + 1) * 16 + quad * 4];
      f32x4 lo = sacc[2 * s], hi = sacc[2 * s + 1];
      pf[s] = bf16x8{
        (bf16)(fexp2(lo[0] * EXP_C1) * iv0.x), (bf16)(fexp2(lo[1] * EXP_C1) * iv0.y),
        (bf16)(fexp2(lo[2] * EXP_C1) * iv0.z), (bf16)(fexp2(lo[3] * EXP_C1) * iv0.w),
        (bf16)(fexp2(hi[0] * EXP_C1) * iv1.x), (bf16)(fexp2(hi[1] * EXP_C1) * iv1.y),
        (bf16)(fexp2(hi[2] * EXP_C1) * iv1.z), (bf16)(fexp2(hi[3] * EXP_C1) * iv1.w) };
    }
    // O += P @ Vc : 16 MFMA, B-frags from permuted Vl.
    for (int s = 0; s < 2; ++s)
      for (int j2 = 0; j2 < 8; ++j2) {
        bf16x8 bv_ = *(const bf16x8*)(Vl + ((s * 4 + quad) * 2 + (j2 >> 2)) * 1024
                                         + ((j2 * 16 + ln) & 63) * 16);
        oacc[j2] = mfma16(pf[s], bv_, oacc[j2]);
      }
  }

  // max over this block's 128 q rows, per output column d
  for (int j2 = 0; j2 < 8; ++j2) {
    float m = fmaxf(fmaxf(oacc[j2][0], oacc[j2][1]), fmaxf(oacc[j2][2], oacc[j2][3]));
    m = fmaxf(m, __shfl_xor(m, 16, 64));
    m = fmaxf(m, __shfl_xor(m, 32, 64));
    if (lane < 16) redm[wave][j2 * 16 + ln] = m;
  }
  __syncthreads();
  if (tid < 128) {
    float m = redm[0][tid];
    for (int w = 1; w < 8; ++w) m = fmaxf(m, redm[w][tid]);
    Opart[((size_t)b * 8 + qt) * 128 + tid] = m;
  }
}

// ============================================================================
// Kernel 4: final 8-way max over q-tiles -> d_out [64,128] fp32
// ============================================================================
__global__ __launch_bounds__(256) void k_final(
    const float* __restrict__ Opart, float* __restrict__ out)
{
  int t = blockIdx.x * 256 + threadIdx.x;       // 8192 outputs
  int b = t >> 7, d = t & 127;
  const float* p = Opart + (size_t)b * 1024 + d;
  float m = p[0];
  for (int i = 1; i < 8; ++i) m = fmaxf(m, p[(size_t)i * 128]);
  out[t] = m;
}

// ============================================================================
extern "C" void kernel_launch(void* const* d_in, const int* in_sizes, int n_in,
                              void* d_out, int out_size, void* d_ws, size_t ws_size,
                              hipStream_t stream) {
  const float* q  = (const float*)d_in[0];
  const float* Wq = (const float*)d_in[1];
  const float* bq = (const float*)d_in[2];
  const float* Wk = (const float*)d_in[3];
  const float* bk = (const float*)d_in[4];
  const float* Wv = (const float*)d_in[5];
  const float* bv = (const float*)d_in[6];
  float* out = (float*)d_out;

  char* ws = (char*)d_ws;
  bf16*  Qb    = (bf16*)(ws);                         // 16 MB granule tiles [s][d]
  bf16*  Kb    = (bf16*)(ws + (16u << 20));           // 16 MB
  bf16*  VT    = (bf16*)(ws + (32u << 20));           // 16 MB (V^T, row-permuted)
  float* inv   = (float*)(ws + (48u << 20));          // 256 KB [64][1024]
  float* Opart = (float*)(ws + (48u << 20) + (512u << 10)); // 256 KB [64][8][128]
  bf16*  Wc    = (bf16*)(ws + (49u << 20));           // 192 KB [3][32][128][8]

  k_prep <<<48,           256, 0, stream>>>(Wq, Wk, Wv, Wc);
  k_qkv  <<<dim3(1024),   256, 0, stream>>>(q, Wc, bq, bk, bv, Qb, Kb, VT);
  k_stats<<<dim3(64, 8),  512, 0, stream>>>(Qb, Kb, inv);
  k_attn <<<dim3(64, 8),  512, 0, stream>>>(Qb, Kb, VT, inv, Opart);
  k_final<<<32, 256, 0, stream>>>(Opart, out);
}